// Round 4
// baseline (307.901 us; speedup 1.0000x reference)
//
#include <hip/hip_runtime.h>
#include <hip/hip_fp16.h>

typedef unsigned int uint;
typedef _Float16 h2 __attribute__((ext_vector_type(2)));

// Fused per-sample dynamic conv network.
// x: (8,3,1024,1024) f32, thumb: (8,3,256,256) f32, feature: (8,492) f32
// out = [x_out flat, thumb flat], f32.
//
// 128x32 tile, 1024 threads, UNIFORM conv geometry: every layer computes
// staged rows 1..40 x local px 2..137 (680 threads = 20 row-pairs x 34
// strips of 4px x 2rows). Garbage creeps inward 1px/layer from the fixed
// border exactly as the needed set shrinks; after 5 layers the valid set
// is exactly the 128x32 output window.
// Layer 5 is FUSED with the epilogue: accs stay in registers; the 512
// threads owning the valid region (cc 1..32, cr 2..17) apply conv1x1 +
// global residual + attention and store straight to global. Deletes one
// barrier, all l4 LDS stores and all epilogue LDS reads.
// LDS 72.6KB/block -> 2 blocks/CU = 32 waves (occupancy cap).
// Conv math packed fp16 (v_pk_fma_f16); epilogue fp32.

#define ROWS   42
#define W_U    72            // LDS row stride (dwords): 70 real + 2 pad
#define W_REAL 70            // staged dwords (140 px) per row
#define CHP_U  (ROWS*W_U)    // 3024 dwords per channel
#define BUF_U  (3*CHP_U)     // 9072 dwords per buffer
#define NST    680           // conv threads: 20 row-pairs x 34 strips

__device__ __forceinline__ h2   U2H(uint u) { return __builtin_bit_cast(h2, u); }
__device__ __forceinline__ uint H2U(h2 h)   { return __builtin_bit_cast(uint, h); }

// ---------------- prep: pack per-sample conv3 weights as {w,w} half2 ----------------
// table layout per sample (stride 448 dwords):
//   [0..404]   conv3 weights, idx = l*81 + ic*27 + ky*9 + oc*3 + kx
//   [405..419] conv3 bias,    idx = 405 + l*3 + oc
__global__ void prep_weights(const float* __restrict__ feat, uint* __restrict__ wtab)
{
    const int b = blockIdx.x;
    const int t = threadIdx.x;
    float w = 0.f;
    bool valid = false;
    if (t < 405) {
        int l = t / 81, r = t % 81;
        int ic = r / 27; r %= 27;
        int ky = r / 9;  r %= 9;
        int oc = r / 3;
        int kx = r % 3;
        w = feat[b * 492 + l * 84 + ((oc * 3 + ic) * 3 + ky) * 3 + kx];
        valid = true;
    } else if (t < 420) {
        int i = t - 405;
        w = feat[b * 492 + (i / 3) * 84 + 81 + (i % 3)];
        valid = true;
    }
    if (valid) {
        _Float16 h = (_Float16)w;
        h2 hh = { h, h };
        wtab[b * 448 + t] = H2U(hh);
    }
}

// ---------------- main fused kernel ----------------
__global__ __launch_bounds__(1024, 8) void fused_net(
    const float* __restrict__ xin,
    const float* __restrict__ thumb,
    const float* __restrict__ feat,
    const uint*  __restrict__ wtab,
    float* __restrict__ out)
{
    const int tid = threadIdx.x;

    // ---- thumb passthrough blocks (whole block exits before any barrier) ----
    if (blockIdx.x == 8) {
        const int part = blockIdx.y + 32 * blockIdx.z;     // 0..255
        const float4* s4 = (const float4*)thumb;
        float4* d4 = (float4*)(out + 25165824ull);
        const int n4 = 1572864 / 4;
        for (int i = part * 1024 + tid; i < n4; i += 256 * 1024)
            d4[i] = s4[i];
        return;
    }

    const int gx0 = blockIdx.x * 128;
    const int gy0 = blockIdx.y * 32;
    const int b   = blockIdx.z;
    const bool edge = (gx0 == 0) | (gx0 == 896) | (gy0 == 0) | (gy0 == 992);
    const float* wf = feat + b * 492;        // uniform fp32 (epilogue)
    const uint*  wt = wtab + b * 448;        // uniform packed half2 (conv)

    __shared__ __align__(16) uint lds[2 * BUF_U + 8];   // 72608 B
    uint* b0 = lds;
    uint* b1 = lds + BUF_U + 4;              // dword offset 9076 -> 16B aligned

    // ---- stage: f32 global -> half2 LDS. dword u <-> gx = gx0-6+2u (even) ----
    // incremental (ch,row,u) walk: idx = tid + 1024*it, 1024 = 14*70 + 44
    const float* xb = xin + ((size_t)(b * 3) << 20);
    {
        int srow = tid / 70;
        int su   = tid - srow * 70;          // tid<1024 -> srow<=14, ch=0
        int sch  = 0;
        if (!edge) {
            #pragma unroll
            for (int it = 0; it < 9; ++it) {
                if (it < 8 || tid < 628) {   // 3*42*70 = 8820 = 8*1024 + 628
                    const float2 f = *(const float2*)(xb + ((size_t)sch << 20) +
                                                      ((size_t)(gy0 - 5 + srow) << 10) +
                                                      (gx0 - 6 + 2 * su));
                    b0[sch * CHP_U + srow * W_U + su] =
                        __builtin_bit_cast(uint, __builtin_amdgcn_cvt_pkrtz(f.x, f.y));
                }
                su += 44; srow += 14;
                if (su >= 70)   { su -= 70; srow += 1; }
                if (srow >= 42) { srow -= 42; sch += 1; }
            }
        } else {
            #pragma unroll
            for (int it = 0; it < 9; ++it) {
                if (it < 8 || tid < 628) {
                    const int gy = gy0 - 5 + srow;
                    const int gx = gx0 - 6 + 2 * su;   // even; gx<1024 => gx+1<=1023
                    float2 f = {0.f, 0.f};
                    if ((unsigned)gy < 1024u && (unsigned)gx < 1024u)
                        f = *(const float2*)(xb + ((size_t)sch << 20) +
                                             ((size_t)gy << 10) + gx);
                    b0[sch * CHP_U + srow * W_U + su] =
                        __builtin_bit_cast(uint, __builtin_amdgcn_cvt_pkrtz(f.x, f.y));
                }
                su += 44; srow += 14;
                if (su >= 70)   { su -= 70; srow += 1; }
                if (srow >= 42) { srow -= 42; sch += 1; }
            }
        }
    }
    __syncthreads();

    // ---- conv thread coords (uniform across layers) ----
    const int cr = tid / 34;                 // 0..19  (valid when tid<680)
    const int cc = tid - cr * 34;            // 0..33
    const int y0 = 1 + 2 * cr;               // staged rows y0,y0+1 in 1..40
    const int x0 = 2 + 4 * cc;               // local px x0..x0+3 in 2..137
    // fused-epilogue set: exactly the valid final region = output window
    const bool ep = (tid < NST) & (cr >= 2) & (cr <= 17) & (cc >= 1) & (cc <= 32);

    // ---- residual pre-read for fused threads (b0 is clobbered at l=1) ----
    uint resA[3][2], resB[3][2];
    if (ep) {
        #pragma unroll
        for (int ch = 0; ch < 3; ++ch)
            #pragma unroll
            for (int j = 0; j < 2; ++j) {
                resA[ch][j] = b0[ch * CHP_U + (y0 + j) * W_U + 1 + 2 * cc];
                resB[ch][j] = b0[ch * CHP_U + (y0 + j) * W_U + 2 + 2 * cc];
            }
    }

    // ---- hoisted border store-masks (edge blocks only; used for l<4) ----
    uint mA[2] = {~0u, ~0u}, mB[2] = {~0u, ~0u};
    if (edge) {
        const int gyA = gy0 - 5 + y0;
        const int gxA = gx0 - 6 + x0;
        const uint mA0 = ((((unsigned)gxA       < 1024u) ? 0x0000ffffu : 0u) |
                          (((unsigned)(gxA + 1) < 1024u) ? 0xffff0000u : 0u));
        const uint mB0 = ((((unsigned)(gxA + 2) < 1024u) ? 0x0000ffffu : 0u) |
                          (((unsigned)(gxA + 3) < 1024u) ? 0xffff0000u : 0u));
        #pragma unroll
        for (int j = 0; j < 2; ++j) {
            const uint mr = ((unsigned)(gyA + j) < 1024u) ? ~0u : 0u;
            mA[j] = mA0 & mr;
            mB[j] = mB0 & mr;
        }
    }

    const h2 c02 = { (_Float16)0.2f, (_Float16)0.2f };

    // ---- 5 conv3x3 residual+leaky layers; l=4 fused with epilogue ----
    #pragma unroll
    for (int l = 0; l < 5; ++l) {
        const uint* sb = (l & 1) ? b1 : b0;
        uint*       db = (l & 1) ? b0 : b1;
        const bool act = (l < 4) ? (tid < NST) : ep;
        if (act) {
            const uint* tb = sb + (y0 - 1) * W_U + 2 * cc;   // even dword -> 8B reads
            h2 accA[2][3], accB[2][3];
            #pragma unroll
            for (int oc = 0; oc < 3; ++oc) {
                const h2 bi = U2H(wt[405 + l * 3 + oc]);
                accA[0][oc] = bi; accA[1][oc] = bi;
                accB[0][oc] = bi; accB[1][oc] = bi;
            }
            #pragma unroll
            for (int ic = 0; ic < 3; ++ic) {
                #pragma unroll
                for (int t = 0; t < 4; ++t) {
                    const uint2 P = *(const uint2*)(tb + ic * CHP_U + t * W_U);
                    const uint2 Q = *(const uint2*)(tb + ic * CHP_U + t * W_U + 2);
                    const uint u0 = P.x, u1 = P.y, u2 = Q.x, u3 = Q.y;
                    const h2 X01 = U2H((u0 >> 16) | (u1 << 16));   // halves {1,2}
                    const h2 C1  = U2H(u1);
                    const h2 X12 = U2H((u1 >> 16) | (u2 << 16));   // halves {3,4}
                    const h2 C2  = U2H(u2);
                    const h2 X23 = U2H((u2 >> 16) | (u3 << 16));   // halves {5,6}
                    #pragma unroll
                    for (int j = 0; j < 2; ++j) {
                        const int ky = t - j;
                        if (0 <= ky && ky <= 2) {
                            const int wb = l * 81 + (ic * 3 + ky) * 9;
                            #pragma unroll
                            for (int oc = 0; oc < 3; ++oc) {
                                const h2 w0 = U2H(wt[wb + oc * 3 + 0]);
                                const h2 w1 = U2H(wt[wb + oc * 3 + 1]);
                                const h2 w2 = U2H(wt[wb + oc * 3 + 2]);
                                accA[j][oc] = __builtin_elementwise_fma(w0, X01, accA[j][oc]);
                                accA[j][oc] = __builtin_elementwise_fma(w1, C1,  accA[j][oc]);
                                accA[j][oc] = __builtin_elementwise_fma(w2, X12, accA[j][oc]);
                                accB[j][oc] = __builtin_elementwise_fma(w0, X12, accB[j][oc]);
                                accB[j][oc] = __builtin_elementwise_fma(w1, C2,  accB[j][oc]);
                                accB[j][oc] = __builtin_elementwise_fma(w2, X23, accB[j][oc]);
                            }
                        }
                    }
                    if (t == 1) { accA[0][ic] = accA[0][ic] + C1; accB[0][ic] = accB[0][ic] + C2; }
                    if (t == 2) { accA[1][ic] = accA[1][ic] + C1; accB[1][ic] = accB[1][ic] + C2; }
                }
            }
            // leaky 0.2 = max(v, 0.2*v)
            #pragma unroll
            for (int j = 0; j < 2; ++j)
                #pragma unroll
                for (int oc = 0; oc < 3; ++oc) {
                    accA[j][oc] = __builtin_elementwise_max(accA[j][oc], c02 * accA[j][oc]);
                    accB[j][oc] = __builtin_elementwise_max(accB[j][oc], c02 * accB[j][oc]);
                }

            if (l < 4) {
                uint* ob = db + y0 * W_U + 1 + 2 * cc;
                if (!edge) {
                    #pragma unroll
                    for (int j = 0; j < 2; ++j)
                        #pragma unroll
                        for (int oc = 0; oc < 3; ++oc) {
                            ob[oc * CHP_U + j * W_U]     = H2U(accA[j][oc]);
                            ob[oc * CHP_U + j * W_U + 1] = H2U(accB[j][oc]);
                        }
                } else {
                    #pragma unroll
                    for (int j = 0; j < 2; ++j)
                        #pragma unroll
                        for (int oc = 0; oc < 3; ++oc) {
                            ob[oc * CHP_U + j * W_U]     = H2U(accA[j][oc]) & mA[j];
                            ob[oc * CHP_U + j * W_U + 1] = H2U(accB[j][oc]) & mB[j];
                        }
                }
            } else {
                // ---- fused epilogue: conv1x1 + global residual + attention ----
                const int gxA = gx0 - 6 + x0;          // = gx0-4+4cc, mult of 4
                float* outb = out + ((size_t)(b * 3) << 20);
                #pragma unroll
                for (int j = 0; j < 2; ++j) {
                    const int gy = gy0 - 5 + y0 + j;   // in [gy0, gy0+31]
                    const float h1 = (float)gy * (1.0f / 1024.0f);
                    const float h2v = h1 * h1, h3 = h2v * h1;
                    #pragma unroll
                    for (int hh = 0; hh < 2; ++hh) {
                        float x5[3][2], rs[3][2];
                        #pragma unroll
                        for (int ch = 0; ch < 3; ++ch) {
                            const h2 a = hh ? accB[j][ch] : accA[j][ch];
                            x5[ch][0] = (float)a.x; x5[ch][1] = (float)a.y;
                            const h2 r = U2H(hh ? resB[ch][j] : resA[ch][j]);
                            rs[ch][0] = (float)r.x; rs[ch][1] = (float)r.y;
                        }
                        float o[3][2];
                        #pragma unroll
                        for (int p = 0; p < 2; ++p) {
                            const float wc = (float)(gxA + 2 * hh + p) * (1.0f / 1024.0f);
                            const float w2 = wc * wc, w3 = w2 * wc;
                            const float hw = h1 * wc, h2w = h2v * wc, hw2 = h1 * w2;
                            #pragma unroll
                            for (int oc = 0; oc < 3; ++oc) {
                                float s = x5[oc][p] + wf[429 + oc]
                                        + wf[420 + oc * 3 + 0] * x5[0][p]
                                        + wf[420 + oc * 3 + 1] * x5[1][p]
                                        + wf[420 + oc * 3 + 2] * x5[2][p];
                                s = s >= 0.f ? s : 0.2f * s;
                                const float xf = rs[oc][p] + s;
                                const float x1 = xf, x2 = x1 * x1, x3 = x2 * x1;
                                const float* cf = wf + 432 + oc * 20;
                                float att =
                                    cf[0] * h3 + cf[1] * h2w + cf[2] * h2v * x1 + cf[3] * h2v +
                                    cf[4] * hw2 + cf[5] * hw * x1 + cf[6] * hw + cf[7] * h1 * x2 +
                                    cf[8] * h1 * x1 + cf[9] * h1 + cf[10] * w3 + cf[11] * w2 * x1 +
                                    cf[12] * w2 + cf[13] * wc * x2 + cf[14] * wc * x1 + cf[15] * wc +
                                    cf[16] * x3 + cf[17] * x2 + cf[18] * x1 + cf[19];
                                o[oc][p] = xf * (1.f + att);
                            }
                        }
                        #pragma unroll
                        for (int oc = 0; oc < 3; ++oc) {
                            float2 v = {o[oc][0], o[oc][1]};
                            *(float2*)&outb[((size_t)oc << 20) + ((size_t)gy << 10) +
                                            (gxA + 2 * hh)] = v;
                        }
                    }
                }
            }
        }
        if (l < 4) __syncthreads();
    }
}

extern "C" void kernel_launch(void* const* d_in, const int* in_sizes, int n_in,
                              void* d_out, int out_size, void* d_ws, size_t ws_size,
                              hipStream_t stream) {
    const float* x     = (const float*)d_in[0];
    const float* thumb = (const float*)d_in[1];
    const float* feat  = (const float*)d_in[2];
    float* out = (float*)d_out;
    uint* wtab = (uint*)d_ws;   // 8 * 448 dwords = 14336 B

    prep_weights<<<dim3(8), 448, 0, stream>>>(feat, wtab);
    dim3 grid(9, 32, 8);        // x==8 blocks do the thumb copy
    fused_net<<<grid, 1024, 0, stream>>>(x, thumb, feat, wtab, out);
}